// Round 7
// baseline (501.678 us; speedup 1.0000x reference)
//
#include <hip/hip_runtime.h>
#include <hip/hip_bf16.h>

typedef unsigned short ushort;
typedef __attribute__((ext_vector_type(8))) short short8;
typedef __attribute__((ext_vector_type(4))) float f32x4;

constexpr int N_  = 4096;
constexpr int TD_ = 768;
constexpr int ID_ = 512;
constexpr int H_  = 256;
constexpr int HD_ = 64;
constexpr int E_  = 131072;
constexpr float QSCALE = 0.125f * 1.44269504088896f;  // 1/sqrt(64) * log2(e)

#define MFMA16(a, b, c) __builtin_amdgcn_mfma_f32_16x16x32_bf16(a, b, c, 0, 0, 0)

__device__ inline ushort f2bf(float x) {
    union { float f; unsigned u; } v; v.f = x;
    unsigned r = v.u + 0x7fff + ((v.u >> 16) & 1);
    return (ushort)(r >> 16);
}
__device__ inline float lo2f(unsigned u) { union { unsigned x; float f; } v; v.x = u << 16; return v.f; }
__device__ inline float hi2f(unsigned u) { union { unsigned x; float f; } v; v.x = u & 0xffff0000u; return v.f; }

__device__ inline float exp2r(float x) {
    float r;
    asm("v_exp_f32 %0, %1" : "=v"(r) : "v"(x));
    return r;
}
__device__ inline unsigned pkbf(float lo, float hi) {
    union { float f; unsigned u; } a, b; a.f = lo; b.f = hi;
    return __builtin_amdgcn_perm(b.u + 0x8000u, a.u + 0x8000u, 0x07060302u);
}

__device__ inline void gl_lds16(const void* g, void* l) {
    __builtin_amdgcn_global_load_lds((const __attribute__((address_space(1))) unsigned int*)g,
                                     (__attribute__((address_space(3))) unsigned int*)l, 16, 0, 0);
}

// Stage a 64x64 bf16 tile into LDS via global_load_lds width=16, XOR-swizzled 16B chunks.
__device__ inline void stage64(const ushort* g, long long strideEl, ushort* lds, int w, int l) {
    int r8 = l >> 3;
    int cc = (l & 7) ^ r8;
    #pragma unroll
    for (int p = 0; p < 2; p++) {
        int row = w * 16 + p * 8 + r8;
        gl_lds16(g + (long long)row * strideEl + cc * 8, lds + (w * 16 + p * 8) * 64);
    }
}
__device__ inline int swz(int row, int kOff) {
    return row * 64 + ((((kOff >> 3) ^ (row & 7))) << 3);
}

union SharedU {
    struct { ushort A[2][4096]; ushort B[2][4096]; ushort C[4608]; } g;   // gemm: 41984 B
    struct { ushort K[2][4096]; ushort V[2][4096]; ushort P[4][1152]; } a; // attn: 41984 B
    struct { float T[64][65]; } p;                                         // transpose
    struct { int sums[256]; } s;                                           // scan
};

struct Params {
    const float *text, *img;
    const int *eidx;
    const float *tw, *tb, *iw, *ib, *wq, *bq, *wk, *bk, *wv, *bv, *wo, *bo;
    const float *g1w, *g1b, *g2w, *g2b, *cw, *cb;
    float* out;
    unsigned* bar;
    float *dinv, *swv;
    int *indeg, *offs, *pos, *ssrc;
    ushort *textbf, *imgbf, *twT, *iwT, *wqT, *wkT, *wvT, *woT, *g1wT, *g2wT;
    ushort *combbf, *Qg, *Kg, *Vtg, *obuf, *attn_out, *hbuf, *g1b16, *hbuf2;
};

// device-wide barrier: monotone counter; all 256 blocks guaranteed co-resident
// (grid 256 <= capacity even at 1 block/CU), so spin cannot deadlock.
__device__ inline void gridbar(unsigned* bar) {
    __syncthreads();
    if (threadIdx.x == 0) {
        __threadfence();
        unsigned tk = __hip_atomic_fetch_add(bar, 1u, __ATOMIC_ACQ_REL, __HIP_MEMORY_SCOPE_AGENT);
        unsigned target = (tk / 256u + 1u) * 256u;
        while (__hip_atomic_load(bar, __ATOMIC_ACQUIRE, __HIP_MEMORY_SCOPE_AGENT) < target)
            __builtin_amdgcn_s_sleep(1);
    }
    __syncthreads();
}

__global__ __launch_bounds__(256, 1) void mega(Params P) {
    __shared__ SharedU sh;
    const int bid = blockIdx.x, t = threadIdx.x;
    const int w = t >> 6, l = t & 63, q = l >> 4, i = l & 15;
    const int* esrc = P.eidx;
    const int* edst = P.eidx + E_;

    // ================= P0: conversions + transposes + zero graph counters =================
    for (int u = bid; u < 2752; u += 256) {
        if (u < 2560) {  // linear bf16 cvt: text | img
            size_t base = ((size_t)u * 256 + t) * 8;
            const size_t TXE = (size_t)N_ * TD_;
            const float* src; ushort* dst;
            if (base < TXE) { src = P.text + base; dst = P.textbf + base; }
            else            { src = P.img + (base - TXE); dst = P.imgbf + (base - TXE); }
            float4 x = *(const float4*)src;
            float4 y = *(const float4*)(src + 4);
            ushort o[8] = { f2bf(x.x), f2bf(x.y), f2bf(x.z), f2bf(x.w),
                            f2bf(y.x), f2bf(y.y), f2bf(y.z), f2bf(y.w) };
            *(short8*)dst = *(const short8*)o;
        } else if (u < 2736) {  // transpose-convert weights
            int wb = u - 2560;
            const float* src; ushort* dst; int R, tile;
            if (wb < 48)       { src = P.tw;  dst = P.twT;  R = 768; tile = wb; }
            else if (wb < 80)  { src = P.iw;  dst = P.iwT;  R = 512; tile = wb - 48; }
            else if (wb < 96)  { src = P.wq;  dst = P.wqT;  R = 256; tile = wb - 80; }
            else if (wb < 112) { src = P.wk;  dst = P.wkT;  R = 256; tile = wb - 96; }
            else if (wb < 128) { src = P.wv;  dst = P.wvT;  R = 256; tile = wb - 112; }
            else if (wb < 144) { src = P.wo;  dst = P.woT;  R = 256; tile = wb - 128; }
            else if (wb < 160) { src = P.g1w; dst = P.g1wT; R = 256; tile = wb - 144; }
            else               { src = P.g2w; dst = P.g2wT; R = 256; tile = wb - 160; }
            const int r0 = (tile >> 2) * 64, c0 = (tile & 3) * 64;
            __syncthreads();
            #pragma unroll
            for (int uu = 0; uu < 16; uu++) {
                int lin = t + uu * 256;
                int r = lin >> 6, c = lin & 63;
                sh.p.T[r][c] = src[(size_t)(r0 + r) * 256 + c0 + c];
            }
            __syncthreads();
            #pragma unroll
            for (int uu = 0; uu < 16; uu++) {
                int lin = t + uu * 256;
                int c = lin >> 6, r = lin & 63;
                dst[(size_t)(c0 + c) * R + r0 + r] = f2bf(sh.p.T[r][c]);
            }
        } else {  // zero indeg/pos (8192 ints over 4 units)
            int zi = u - 2736;
            if (zi < 4) {
                int* d0 = (zi < 2) ? P.indeg + zi * 2048 : P.pos + (zi - 2) * 2048;
                #pragma unroll
                for (int k2 = 0; k2 < 8; k2++) d0[t * 8 + k2] = 0;
            }
        }
    }
    gridbar(P.bar);

    // ================= P1: edge count + combined projection =================
    {
        int e = bid * 512 + t;
        atomicAdd(&P.indeg[edst[e]], 1);
        atomicAdd(&P.indeg[edst[e + 256]], 1);
    }
    {
        const int bm = (bid >> 2) * 64, bn = (bid & 3) * 64;
        constexpr int NCH = 20;
        auto stageC = [&](int c, int buf) {
            if (c < 12) {
                stage64(P.textbf + (size_t)bm * TD_ + c * 64, TD_, sh.g.A[buf], w, l);
                stage64(P.twT + (size_t)bn * TD_ + c * 64, TD_, sh.g.B[buf], w, l);
            } else {
                int cc = c - 12;
                stage64(P.imgbf + (size_t)bm * ID_ + cc * 64, ID_, sh.g.A[buf], w, l);
                stage64(P.iwT + (size_t)bn * ID_ + cc * 64, ID_, sh.g.B[buf], w, l);
            }
        };
        f32x4 acc1[4], acc2[4];
        #pragma unroll
        for (int nt = 0; nt < 4; nt++) { acc1[nt] = (f32x4){0,0,0,0}; acc2[nt] = (f32x4){0,0,0,0}; }
        stageC(0, 0);
        for (int c = 0; c < NCH; c++) {
            __syncthreads();
            if (c + 1 < NCH) stageC(c + 1, (c + 1) & 1);
            const ushort* Ab = sh.g.A[c & 1];
            const ushort* Bb = sh.g.B[c & 1];
            f32x4* acc = (c < 12) ? acc1 : acc2;
            #pragma unroll
            for (int kb = 0; kb < 2; kb++) {
                short8 af = *(const short8*)&Ab[swz(w * 16 + i, kb * 32 + q * 8)];
                #pragma unroll
                for (int nt = 0; nt < 4; nt++) {
                    short8 bfr = *(const short8*)&Bb[swz(nt * 16 + i, kb * 32 + q * 8)];
                    acc[nt] = MFMA16(af, bfr, acc[nt]);
                }
            }
        }
        __syncthreads();
        #pragma unroll
        for (int nt = 0; nt < 4; nt++) {
            float b1 = P.tb[bn + nt * 16 + i], b2 = P.ib[bn + nt * 16 + i];
            #pragma unroll
            for (int r = 0; r < 4; r++) {
                float v = fmaxf(acc1[nt][r] + b1, 0.f) + fmaxf(acc2[nt][r] + b2, 0.f);
                sh.g.C[(w * 16 + q * 4 + r) * 72 + nt * 16 + i] = f2bf(v);
            }
        }
        __syncthreads();
        int rr = t >> 2, c16 = (t & 3) * 16;
        short8 v0 = *(const short8*)&sh.g.C[rr * 72 + c16];
        short8 v1 = *(const short8*)&sh.g.C[rr * 72 + c16 + 8];
        ushort* dst = P.combbf + (size_t)(bm + rr) * H_ + bn + c16;
        *(short8*)dst = v0;
        *(short8*)(dst + 8) = v1;
    }
    gridbar(P.bar);

    // ================= P2: QKV (x3 per block) + degree scan (block 0) =================
    {
        const int bm = (bid >> 2) * 64, head = bid & 3;
        for (int z = 0; z < 3; z++) {
            const ushort* WT = (z == 0) ? P.wqT : (z == 1) ? P.wkT : P.wvT;
            const float* bias = (z == 0) ? P.bq : (z == 1) ? P.bk : P.bv;
            f32x4 acc[4];
            #pragma unroll
            for (int nt = 0; nt < 4; nt++) acc[nt] = (f32x4){0,0,0,0};
            stage64(P.combbf + (size_t)bm * H_, H_, sh.g.A[0], w, l);
            stage64(WT + (size_t)(head * 64) * H_, H_, sh.g.B[0], w, l);
            for (int c = 0; c < 4; c++) {
                __syncthreads();
                if (c < 3) {
                    stage64(P.combbf + (size_t)bm * H_ + (c + 1) * 64, H_, sh.g.A[(c + 1) & 1], w, l);
                    stage64(WT + (size_t)(head * 64) * H_ + (c + 1) * 64, H_, sh.g.B[(c + 1) & 1], w, l);
                }
                const ushort* Ab = sh.g.A[c & 1];
                const ushort* Bb = sh.g.B[c & 1];
                #pragma unroll
                for (int kb = 0; kb < 2; kb++) {
                    short8 af = *(const short8*)&Ab[swz(w * 16 + i, kb * 32 + q * 8)];
                    #pragma unroll
                    for (int nt = 0; nt < 4; nt++) {
                        short8 bfr = *(const short8*)&Bb[swz(nt * 16 + i, kb * 32 + q * 8)];
                        acc[nt] = MFMA16(af, bfr, acc[nt]);
                    }
                }
            }
            __syncthreads();
            #pragma unroll
            for (int nt = 0; nt < 4; nt++) {
                float bv_ = bias[head * 64 + nt * 16 + i];
                #pragma unroll
                for (int r = 0; r < 4; r++) {
                    float v = acc[nt][r] + bv_;
                    if (z == 0) v *= QSCALE;
                    if (z < 2) sh.g.C[(w * 16 + q * 4 + r) * 72 + nt * 16 + i] = f2bf(v);
                    else       sh.g.C[(nt * 16 + i) * 72 + w * 16 + q * 4 + r] = f2bf(v);
                }
            }
            __syncthreads();
            int rr = t >> 2, c16 = (t & 3) * 16;
            short8 v0 = *(const short8*)&sh.g.C[rr * 72 + c16];
            short8 v1 = *(const short8*)&sh.g.C[rr * 72 + c16 + 8];
            ushort* dst;
            if (z < 2) dst = ((z == 0) ? P.Qg : P.Kg) + (size_t)head * N_ * HD_ + (size_t)(bm + rr) * HD_ + c16;
            else       dst = P.Vtg + (size_t)head * HD_ * N_ + (size_t)rr * N_ + bm + c16;
            *(short8*)dst = v0;
            *(short8*)(dst + 8) = v1;
        }
    }
    if (bid == 0) {  // exclusive scan of indeg + dinv
        __syncthreads();
        int v[16]; int ssum = 0; int base = t * 16;
        #pragma unroll
        for (int k2 = 0; k2 < 16; k2++) { v[k2] = P.indeg[base + k2]; ssum += v[k2]; }
        sh.s.sums[t] = ssum;
        __syncthreads();
        for (int off = 1; off < 256; off <<= 1) {
            int x = (t >= off) ? sh.s.sums[t - off] : 0;
            __syncthreads();
            sh.s.sums[t] += x;
            __syncthreads();
        }
        int excl = sh.s.sums[t] - ssum;
        #pragma unroll
        for (int k2 = 0; k2 < 16; k2++) {
            P.offs[base + k2] = excl;
            excl += v[k2];
            P.dinv[base + k2] = 1.f / sqrtf((float)(v[k2] + 1));
        }
    }
    gridbar(P.bar);

    // ================= P3: edge scatter + full flash attention =================
    {
        #pragma unroll
        for (int rep = 0; rep < 2; rep++) {
            int ee = bid * 512 + t + rep * 256;
            int s = esrc[ee], d = edst[ee];
            int p_ = atomicAdd(&P.pos[d], 1);
            int idx = P.offs[d] + p_;
            P.ssrc[idx] = s;
            P.swv[idx] = P.dinv[s] * P.dinv[d];
        }
    }
    {
        const int head = bid & 3, r0 = (bid >> 2) * 64;
        const int rw = (i ^ (i >> 1)) & 7;
        ushort* Pw = &sh.a.P[w][0];
        short8 qf[2];
        #pragma unroll
        for (int kb = 0; kb < 2; kb++)
            qf[kb] = *(const short8*)(P.Qg + ((size_t)head * N_ + r0 + w * 16 + i) * HD_ + kb * 32 + q * 8);
        f32x4 Oacc[4];
        float lacc = 0.f;
        #pragma unroll
        for (int dt = 0; dt < 4; dt++) Oacc[dt] = (f32x4){0, 0, 0, 0};

        stage64(P.Kg + (size_t)head * N_ * HD_, HD_, sh.a.K[0], w, l);
        stage64(P.Vtg + (size_t)head * HD_ * N_, N_, sh.a.V[0], w, l);
        for (int it = 0; it < 64; it++) {
            __syncthreads();
            if (it + 1 < 64) {
                stage64(P.Kg + ((size_t)head * N_ + (size_t)(it + 1) * 64) * HD_, HD_, sh.a.K[(it + 1) & 1], w, l);
                stage64(P.Vtg + (size_t)head * HD_ * N_ + (it + 1) * 64, N_, sh.a.V[(it + 1) & 1], w, l);
            }
            const ushort* Kb = sh.a.K[it & 1];
            const ushort* Vb = sh.a.V[it & 1];

            f32x4 St[4];
            #pragma unroll
            for (int kt = 0; kt < 4; kt++) St[kt] = (f32x4){0, 0, 0, 0};
            #pragma unroll
            for (int kb = 0; kb < 2; kb++) {
                #pragma unroll
                for (int kt = 0; kt < 4; kt++) {
                    short8 kf = *(const short8*)&Kb[swz(kt * 16 + i, kb * 32 + q * 8)];
                    St[kt] = MFMA16(kf, qf[kb], St[kt]);
                }
            }
            #pragma unroll
            for (int kt = 0; kt < 4; kt++) {
                float p0 = exp2r(St[kt][0]), p1 = exp2r(St[kt][1]);
                float p2 = exp2r(St[kt][2]), p3 = exp2r(St[kt][3]);
                lacc += (p0 + p1) + (p2 + p3);
                int off = i * 72 + (((2 * kt + (q >> 1)) ^ rw) << 3) + ((q & 1) << 2);
                uint2 v; v.x = pkbf(p0, p1); v.y = pkbf(p2, p3);
                *(uint2*)&Pw[off] = v;
            }
            #pragma unroll
            for (int kb = 0; kb < 2; kb++) {
                short8 pf = *(const short8*)&Pw[i * 72 + (((4 * kb + q) ^ rw) << 3)];
                #pragma unroll
                for (int dt = 0; dt < 4; dt++) {
                    short8 vf = *(const short8*)&Vb[swz(dt * 16 + i, kb * 32 + q * 8)];
                    Oacc[dt] = MFMA16(vf, pf, Oacc[dt]);
                }
            }
        }
        lacc += __shfl_xor(lacc, 16);
        lacc += __shfl_xor(lacc, 32);
        float inv = 1.f / lacc;
        const int row = r0 + w * 16 + i;
        #pragma unroll
        for (int dt = 0; dt < 4; dt++) {
            uint2 v;
            v.x = pkbf(Oacc[dt][0] * inv, Oacc[dt][1] * inv);
            v.y = pkbf(Oacc[dt][2] * inv, Oacc[dt][3] * inv);
            *(uint2*)&P.obuf[(size_t)row * H_ + head * HD_ + dt * 16 + q * 4] = v;
        }
    }
    gridbar(P.bar);

    // ================= GEMM phases =================
    auto gemmP = [&](const ushort* A, const ushort* BT, const float* bias, ushort* outb) {
        const int bm = (bid >> 2) * 64, bn = (bid & 3) * 64;
        f32x4 acc[4];
        #pragma unroll
        for (int nt = 0; nt < 4; nt++) acc[nt] = (f32x4){0, 0, 0, 0};
        stage64(A + (size_t)bm * H_, H_, sh.g.A[0], w, l);
        stage64(BT + (size_t)bn * H_, H_, sh.g.B[0], w, l);
        for (int c = 0; c < 4; c++) {
            __syncthreads();
            if (c < 3) {
                stage64(A + (size_t)bm * H_ + (c + 1) * 64, H_, sh.g.A[(c + 1) & 1], w, l);
                stage64(BT + (size_t)bn * H_ + (c + 1) * 64, H_, sh.g.B[(c + 1) & 1], w, l);
            }
            const ushort* Ab = sh.g.A[c & 1];
            const ushort* Bb = sh.g.B[c & 1];
            #pragma unroll
            for (int kb = 0; kb < 2; kb++) {
                short8 af = *(const short8*)&Ab[swz(w * 16 + i, kb * 32 + q * 8)];
                #pragma unroll
                for (int nt = 0; nt < 4; nt++) {
                    short8 bfr = *(const short8*)&Bb[swz(nt * 16 + i, kb * 32 + q * 8)];
                    acc[nt] = MFMA16(af, bfr, acc[nt]);
                }
            }
        }
        __syncthreads();
        #pragma unroll
        for (int nt = 0; nt < 4; nt++) {
            float bb = bias ? bias[bn + nt * 16 + i] : 0.f;
            #pragma unroll
            for (int r = 0; r < 4; r++)
                sh.g.C[(w * 16 + q * 4 + r) * 72 + nt * 16 + i] = f2bf(acc[nt][r] + bb);
        }
        __syncthreads();
        int rr = t >> 2, c16 = (t & 3) * 16;
        short8 v0 = *(const short8*)&sh.g.C[rr * 72 + c16];
        short8 v1 = *(const short8*)&sh.g.C[rr * 72 + c16 + 8];
        ushort* dst = outb + (size_t)(bm + rr) * H_ + bn + c16;
        *(short8*)dst = v0;
        *(short8*)(dst + 8) = v1;
    };

    auto gather = [&](const ushort* h, int j, float& a0, float& a1, float& a2, float& a3) {
        const int d0 = l * 4;
        float dj = P.dinv[j];
        float s2 = dj * dj;
        uint2 hv = *(const uint2*)&h[(size_t)j * H_ + d0];
        a0 = s2 * lo2f(hv.x); a1 = s2 * hi2f(hv.x);
        a2 = s2 * lo2f(hv.y); a3 = s2 * hi2f(hv.y);
        int start = P.offs[j], cnt = P.indeg[j];
        for (int e = 0; e < cnt; e++) {
            int s = P.ssrc[start + e];
            float wg = P.swv[start + e];
            uint2 v = *(const uint2*)&h[(size_t)s * H_ + d0];
            a0 += wg * lo2f(v.x); a1 += wg * hi2f(v.x);
            a2 += wg * lo2f(v.y); a3 += wg * hi2f(v.y);
        }
    };

    // P4: attn_out = obuf @ woT + bo
    gemmP(P.obuf, P.woT, P.bo, P.attn_out);
    gridbar(P.bar);
    // P5: hbuf = attn_out @ g1wT
    gemmP(P.attn_out, P.g1wT, nullptr, P.hbuf);
    gridbar(P.bar);
    // P6: g1 = relu(agg(hbuf) + g1b)
    {
        #pragma unroll
        for (int k2 = 0; k2 < 4; k2++) {
            int j = bid * 16 + w * 4 + k2;
            float a0, a1, a2, a3;
            gather(P.hbuf, j, a0, a1, a2, a3);
            const int d0 = l * 4;
            a0 = fmaxf(a0 + P.g1b[d0], 0.f);
            a1 = fmaxf(a1 + P.g1b[d0 + 1], 0.f);
            a2 = fmaxf(a2 + P.g1b[d0 + 2], 0.f);
            a3 = fmaxf(a3 + P.g1b[d0 + 3], 0.f);
            uint2 o; o.x = pkbf(a0, a1); o.y = pkbf(a2, a3);
            *(uint2*)&P.g1b16[(size_t)j * H_ + d0] = o;
        }
    }
    gridbar(P.bar);
    // P7: hbuf2 = g1 @ g2wT
    gemmP(P.g1b16, P.g2wT, nullptr, P.hbuf2);
    gridbar(P.bar);
    // P8: out = (agg(hbuf2) + g2b) @ cls_w + cls_b
    {
        #pragma unroll
        for (int k2 = 0; k2 < 4; k2++) {
            int j = bid * 16 + w * 4 + k2;
            float a0, a1, a2, a3;
            gather(P.hbuf2, j, a0, a1, a2, a3);
            const int d0 = l * 4;
            a0 += P.g2b[d0]; a1 += P.g2b[d0 + 1]; a2 += P.g2b[d0 + 2]; a3 += P.g2b[d0 + 3];
            float p0 = a0 * P.cw[d0 * 3 + 0] + a1 * P.cw[(d0 + 1) * 3 + 0]
                     + a2 * P.cw[(d0 + 2) * 3 + 0] + a3 * P.cw[(d0 + 3) * 3 + 0];
            float p1 = a0 * P.cw[d0 * 3 + 1] + a1 * P.cw[(d0 + 1) * 3 + 1]
                     + a2 * P.cw[(d0 + 2) * 3 + 1] + a3 * P.cw[(d0 + 3) * 3 + 1];
            float p2 = a0 * P.cw[d0 * 3 + 2] + a1 * P.cw[(d0 + 1) * 3 + 2]
                     + a2 * P.cw[(d0 + 2) * 3 + 2] + a3 * P.cw[(d0 + 3) * 3 + 2];
            #pragma unroll
            for (int off = 32; off > 0; off >>= 1) {
                p0 += __shfl_xor(p0, off);
                p1 += __shfl_xor(p1, off);
                p2 += __shfl_xor(p2, off);
            }
            if (l == 0) {
                P.out[j * 3 + 0] = p0 + P.cb[0];
                P.out[j * 3 + 1] = p1 + P.cb[1];
                P.out[j * 3 + 2] = p2 + P.cb[2];
            }
        }
    }
}

// ---------------- launch ----------------

extern "C" void kernel_launch(void* const* d_in, const int* in_sizes, int n_in,
                              void* d_out, int out_size, void* d_ws, size_t ws_size,
                              hipStream_t stream) {
    char* W = (char*)d_ws;
    size_t cur = 0;
    auto alloc = [&](size_t sz) { char* p = W + cur; cur += (sz + 255) & ~(size_t)255; return p; };

    Params P;
    P.text = (const float*)d_in[0];
    P.img  = (const float*)d_in[1];
    P.eidx = (const int*)d_in[2];
    P.tw  = (const float*)d_in[3];  P.tb = (const float*)d_in[4];
    P.iw  = (const float*)d_in[5];  P.ib = (const float*)d_in[6];
    P.wq  = (const float*)d_in[7];  P.bq = (const float*)d_in[8];
    P.wk  = (const float*)d_in[9];  P.bk = (const float*)d_in[10];
    P.wv  = (const float*)d_in[11]; P.bv = (const float*)d_in[12];
    P.wo  = (const float*)d_in[13]; P.bo = (const float*)d_in[14];
    P.g1w = (const float*)d_in[15]; P.g1b = (const float*)d_in[16];
    P.g2w = (const float*)d_in[17]; P.g2b = (const float*)d_in[18];
    P.cw  = (const float*)d_in[19]; P.cb = (const float*)d_in[20];
    P.out = (float*)d_out;

    P.bar    = (unsigned*)alloc(256);
    P.dinv   = (float*)alloc(N_ * 4);
    P.swv    = (float*)alloc(E_ * 4);
    P.indeg  = (int*)alloc(N_ * 4);
    P.offs   = (int*)alloc(N_ * 4);
    P.pos    = (int*)alloc(N_ * 4);
    P.ssrc   = (int*)alloc(E_ * 4);
    P.textbf = (ushort*)alloc((size_t)N_ * TD_ * 2);
    P.imgbf  = (ushort*)alloc((size_t)N_ * ID_ * 2);
    P.twT    = (ushort*)alloc((size_t)TD_ * H_ * 2);
    P.iwT    = (ushort*)alloc((size_t)ID_ * H_ * 2);
    P.wqT    = (ushort*)alloc((size_t)H_ * H_ * 2);
    P.wkT    = (ushort*)alloc((size_t)H_ * H_ * 2);
    P.wvT    = (ushort*)alloc((size_t)H_ * H_ * 2);
    P.woT    = (ushort*)alloc((size_t)H_ * H_ * 2);
    P.g1wT   = (ushort*)alloc((size_t)H_ * H_ * 2);
    P.g2wT   = (ushort*)alloc((size_t)H_ * H_ * 2);
    P.combbf = (ushort*)alloc((size_t)N_ * H_ * 2);
    P.Qg     = (ushort*)alloc((size_t)N_ * H_ * 2);
    P.Kg     = (ushort*)alloc((size_t)N_ * H_ * 2);
    P.Vtg    = (ushort*)alloc((size_t)N_ * H_ * 2);
    P.obuf   = (ushort*)alloc((size_t)N_ * H_ * 2);
    P.attn_out = (ushort*)alloc((size_t)N_ * H_ * 2);
    P.hbuf   = (ushort*)alloc((size_t)N_ * H_ * 2);
    P.g1b16  = (ushort*)alloc((size_t)N_ * H_ * 2);
    P.hbuf2  = (ushort*)alloc((size_t)N_ * H_ * 2);

    hipMemsetAsync(P.bar, 0, sizeof(unsigned), stream);
    mega<<<dim3(256), dim3(256), 0, stream>>>(P);
}